// Round 1
// baseline (217.010 us; speedup 1.0000x reference)
//
#include <hip/hip_runtime.h>

#define CIN   256
#define COUT  256
#define NB    32
#define HIN   64
#define WIN   64
#define SPATIAL_OUT 16384.0f   // 128*128
#define MULT  2.0f

// ---------------------------------------------------------------------------
// Kernel 1: per (b,c) 64x64 tile -> {Sx, Row0, Col0, X00}
// One block of 256 threads per tile; 1024 float4 loads per tile (4/thread).
// ---------------------------------------------------------------------------
__global__ __launch_bounds__(256) void reduce_x_kernel(
    const float* __restrict__ x, float* __restrict__ xs)
{
    const int bc = blockIdx.x;                          // b*256 + c, 0..8191
    const float4* p = (const float4*)(x + (size_t)bc * (HIN * WIN));
    const int t = threadIdx.x;

    float s_all = 0.f, s_r0 = 0.f, s_c0 = 0.f, x00 = 0.f;
#pragma unroll
    for (int i = 0; i < 4; ++i) {
        const int idx = t + 256 * i;                    // float4 index 0..1023
        const float4 v = p[idx];
        s_all += v.x + v.y + v.z + v.w;
        if (idx < 16)        s_r0 += v.x + v.y + v.z + v.w; // row h=0: floats 0..63
        if ((idx & 15) == 0) s_c0 += v.x;                   // col w=0: float h*64
        if (idx == 0)        x00 = v.x;                     // only thread 0 holds it
    }

    // 64-lane wave reduce
#pragma unroll
    for (int off = 32; off > 0; off >>= 1) {
        s_all += __shfl_down(s_all, off);
        s_r0  += __shfl_down(s_r0,  off);
        s_c0  += __shfl_down(s_c0,  off);
    }

    __shared__ float red[4][3];
    const int wave = t >> 6, lane = t & 63;
    if (lane == 0) { red[wave][0] = s_all; red[wave][1] = s_r0; red[wave][2] = s_c0; }
    __syncthreads();
    if (t == 0) {
        float a = 0.f, r = 0.f, c = 0.f;
#pragma unroll
        for (int w = 0; w < 4; ++w) { a += red[w][0]; r += red[w][1]; c += red[w][2]; }
        float4 o; o.x = a; o.y = r; o.z = c; o.w = x00;
        ((float4*)xs)[bc] = o;
    }
}

// ---------------------------------------------------------------------------
// Kernel 2: per (c,o) weight 3x3 -> {Wsum, Wr(kh=0), Wc(kw=0), W00}
// Output layout [c][stat][o] so kernel 3 reads coalesce over o.
// ---------------------------------------------------------------------------
__global__ __launch_bounds__(256) void reduce_w_kernel(
    const float* __restrict__ w, float* __restrict__ ws)
{
    const int co = blockIdx.x * 256 + threadIdx.x;      // c*256 + o
    const float* p = w + (size_t)co * 9;
    const float w0 = p[0], w1 = p[1], w2 = p[2],
                w3 = p[3], w4 = p[4], w5 = p[5],
                w6 = p[6], w7 = p[7], w8 = p[8];
    const float wsum = w0 + w1 + w2 + w3 + w4 + w5 + w6 + w7 + w8;
    const float wr   = w0 + w1 + w2;   // kh = 0 row
    const float wc   = w0 + w3 + w6;   // kw = 0 col
    const int c = co >> 8, o = co & 255;
    ws[(c * 4 + 0) * 256 + o] = wsum;
    ws[(c * 4 + 1) * 256 + o] = wr;
    ws[(c * 4 + 2) * 256 + o] = wc;
    ws[(c * 4 + 3) * 256 + o] = w0;
}

// ---------------------------------------------------------------------------
// Kernel 3: out[b,o] = 2 * ( (1/16384) * sum_c (Sx*Wsum - Row0*Wr - Col0*Wc
//                                               + X00*W00) + bias[o] )
// One block per b (32 blocks, 256 threads = one o each). xs[b][*] in LDS.
// ---------------------------------------------------------------------------
__global__ __launch_bounds__(256) void finalize_kernel(
    const float* __restrict__ xs, const float* __restrict__ ws,
    const float* __restrict__ bias, float* __restrict__ out)
{
    const int b = blockIdx.x, o = threadIdx.x;
    __shared__ float4 sx[CIN];
    sx[o] = ((const float4*)xs)[b * CIN + o];
    __syncthreads();

    float acc = 0.f;
#pragma unroll 4
    for (int c = 0; c < CIN; ++c) {
        const float4 s = sx[c];                          // broadcast, no conflict
        const float wsum = ws[(c * 4 + 0) * 256 + o];
        const float wr   = ws[(c * 4 + 1) * 256 + o];
        const float wc   = ws[(c * 4 + 2) * 256 + o];
        const float w00  = ws[(c * 4 + 3) * 256 + o];
        acc += s.x * wsum - s.y * wr - s.z * wc + s.w * w00;
    }
    out[b * 256 + o] = MULT * (acc * (1.0f / SPATIAL_OUT) + bias[o]);
}

// ---------------------------------------------------------------------------
extern "C" void kernel_launch(void* const* d_in, const int* in_sizes, int n_in,
                              void* d_out, int out_size, void* d_ws, size_t ws_size,
                              hipStream_t stream)
{
    const float* x      = (const float*)d_in[0];   // (32,256,64,64)
    const float* weight = (const float*)d_in[1];   // (256,256,3,3)
    const float* bias   = (const float*)d_in[2];   // (256,)
    float* out = (float*)d_out;                    // (32,256,1,1)

    float* xs = (float*)d_ws;                              // 8192 * 4 floats = 128 KiB
    float* ws = xs + (size_t)NB * CIN * 4;                 // 256*4*256 floats = 1 MiB

    reduce_x_kernel<<<NB * CIN, 256, 0, stream>>>(x, xs);
    reduce_w_kernel<<<CIN, 256, 0, stream>>>(weight, ws);
    finalize_kernel<<<NB, 256, 0, stream>>>(xs, ws, bias, out);
}

// Round 2
// 200.824 us; speedup vs baseline: 1.0806x; 1.0806x over previous
//
#include <hip/hip_runtime.h>

#define CIN   256
#define COUT  256
#define NB    32
#define HIN   64
#define WIN   64
#define INV_SPATIAL (1.0f / 16384.0f)   // 1/(128*128)
#define MULT  2.0f

// ---------------------------------------------------------------------------
// Kernel 1 (fused): blocks [0, 8192) reduce one (b,c) 64x64 x-tile to
// {Sx, Row0(h=0), Col0(w=0), X00}; blocks [8192, 8448) reduce one c-slice of
// weight to per-(c,o) {Wsum, Wr(kh=0), Wc(kw=0), W00} packed as float4 so the
// finalize kernel does ONE vector load per (c,o).
// ---------------------------------------------------------------------------
__global__ __launch_bounds__(256) void stats_kernel(
    const float* __restrict__ x, const float* __restrict__ w,
    float4* __restrict__ xs, float4* __restrict__ ws4)
{
    const int blk = blockIdx.x;
    const int t   = threadIdx.x;

    if (blk < NB * CIN) {
        // ---- x tile reduce ----
        const float4* p = (const float4*)(x + (size_t)blk * (HIN * WIN));
        float s_all = 0.f, s_r0 = 0.f, s_c0 = 0.f, x00 = 0.f;
#pragma unroll
        for (int i = 0; i < 4; ++i) {
            const int idx = t + 256 * i;                 // float4 index 0..1023
            const float4 v = p[idx];
            s_all += v.x + v.y + v.z + v.w;
            if (idx < 16)        s_r0 += v.x + v.y + v.z + v.w; // row h=0
            if ((idx & 15) == 0) s_c0 += v.x;                   // col w=0
            if (idx == 0)        x00 = v.x;
        }
#pragma unroll
        for (int off = 32; off > 0; off >>= 1) {
            s_all += __shfl_down(s_all, off);
            s_r0  += __shfl_down(s_r0,  off);
            s_c0  += __shfl_down(s_c0,  off);
        }
        __shared__ float red[4][3];
        const int wave = t >> 6, lane = t & 63;
        if (lane == 0) { red[wave][0] = s_all; red[wave][1] = s_r0; red[wave][2] = s_c0; }
        __syncthreads();
        if (t == 0) {
            float a = 0.f, r = 0.f, c = 0.f;
#pragma unroll
            for (int wv = 0; wv < 4; ++wv) { a += red[wv][0]; r += red[wv][1]; c += red[wv][2]; }
            float4 o4; o4.x = a; o4.y = r; o4.z = c; o4.w = x00;
            xs[blk] = o4;
        }
    } else {
        // ---- weight reduce: c = blk - 8192, o = t ----
        const int c = blk - NB * CIN;
        const float* p = w + ((size_t)c * COUT + t) * 9;
        const float w0 = p[0], w1 = p[1], w2 = p[2],
                    w3 = p[3], w4 = p[4], w5 = p[5],
                    w6 = p[6], w7 = p[7], w8 = p[8];
        float4 o4;
        o4.x = w0 + w1 + w2 + w3 + w4 + w5 + w6 + w7 + w8; // Wsum
        o4.y = w0 + w1 + w2;                               // Wr (kh=0)
        o4.z = w0 + w3 + w6;                               // Wc (kw=0)
        o4.w = w0;                                         // W00
        ws4[c * COUT + t] = o4;
    }
}

// ---------------------------------------------------------------------------
// Kernel 2: out[b,o] = 2*( (1/16384)*sum_c(Sx*Wsum - Row0*Wr - Col0*Wc
//                                          + X00*W00) + bias[o] )
// One block per b, 1024 threads: thread (seg,o) sums 64 c's, LDS-reduce 4 segs.
// 512 waves device-wide (2/CU); one float4 L2 load per (c,o) iteration.
// ---------------------------------------------------------------------------
__global__ __launch_bounds__(1024) void finalize_kernel(
    const float4* __restrict__ xs, const float4* __restrict__ ws4,
    const float* __restrict__ bias, float* __restrict__ out)
{
    const int b   = blockIdx.x;
    const int t   = threadIdx.x;
    const int o   = t & 255;
    const int seg = t >> 8;                               // 0..3

    __shared__ float4 sx[CIN];
    __shared__ float  part[4][COUT];
    if (t < CIN) sx[t] = xs[b * CIN + t];
    __syncthreads();

    float acc = 0.f;
    const int c0 = seg * 64;
#pragma unroll 8
    for (int i = 0; i < 64; ++i) {
        const int c = c0 + i;
        const float4 s  = sx[c];                          // wave-uniform broadcast
        const float4 wv = ws4[c * COUT + o];              // coalesced float4
        acc += s.x * wv.x - s.y * wv.y - s.z * wv.z + s.w * wv.w;
    }
    part[seg][o] = acc;
    __syncthreads();
    if (t < COUT) {
        const float a = part[0][t] + part[1][t] + part[2][t] + part[3][t];
        out[b * COUT + t] = MULT * (a * INV_SPATIAL + bias[t]);
    }
}

// ---------------------------------------------------------------------------
extern "C" void kernel_launch(void* const* d_in, const int* in_sizes, int n_in,
                              void* d_out, int out_size, void* d_ws, size_t ws_size,
                              hipStream_t stream)
{
    const float* x      = (const float*)d_in[0];   // (32,256,64,64)
    const float* weight = (const float*)d_in[1];   // (256,256,3,3)
    const float* bias   = (const float*)d_in[2];   // (256,)
    float* out = (float*)d_out;                    // (32,256,1,1)

    float4* xs  = (float4*)d_ws;                   // 8192 float4 = 128 KiB
    float4* ws4 = xs + (size_t)NB * CIN;           // 65536 float4 = 1 MiB

    stats_kernel<<<NB * CIN + CIN, 256, 0, stream>>>(x, weight, xs, ws4);
    finalize_kernel<<<NB, 1024, 0, stream>>>(xs, ws4, bias, out);
}

// Round 4
// 186.422 us; speedup vs baseline: 1.1641x; 1.0773x over previous
//
#include <hip/hip_runtime.h>

#define CIN   256
#define COUT  256
#define NB    32
#define HIN   64
#define WIN   64
#define INV_SPATIAL (1.0f / 16384.0f)   // 1/(128*128)
#define MULT  2.0f

typedef float vfloat4 __attribute__((ext_vector_type(4)));  // clang-native, NT-load OK

// ---------------------------------------------------------------------------
// Kernel 1 (fused): blocks [0, 8192) reduce one (b,c) 64x64 x-tile to
// {Sx, Row0(h=0), Col0(w=0), X00}; blocks [8192, 8448) reduce one c-slice of
// weight to per-(c,o) {Wsum, Wr(kh=0), Wc(kw=0), W00} packed as float4.
// x is streamed once -> non-temporal loads (no L2 fill contention).
// ---------------------------------------------------------------------------
__global__ __launch_bounds__(256) void stats_kernel(
    const float* __restrict__ x, const float* __restrict__ w,
    float4* __restrict__ xs, float4* __restrict__ ws4)
{
    const int blk = blockIdx.x;
    const int t   = threadIdx.x;

    if (blk < NB * CIN) {
        // ---- x tile reduce ----
        const vfloat4* p = (const vfloat4*)(x + (size_t)blk * (HIN * WIN));
        float s_all = 0.f, s_r0 = 0.f, s_c0 = 0.f, x00 = 0.f;
#pragma unroll
        for (int i = 0; i < 4; ++i) {
            const int idx = t + 256 * i;                 // float4 index 0..1023
            const vfloat4 v = __builtin_nontemporal_load(p + idx);
            s_all += v.x + v.y + v.z + v.w;
            if (idx < 16)        s_r0 += v.x + v.y + v.z + v.w; // row h=0
            if ((idx & 15) == 0) s_c0 += v.x;                   // col w=0
            if (idx == 0)        x00 = v.x;
        }
#pragma unroll
        for (int off = 32; off > 0; off >>= 1) {
            s_all += __shfl_down(s_all, off);
            s_r0  += __shfl_down(s_r0,  off);
            s_c0  += __shfl_down(s_c0,  off);
        }
        __shared__ float red[4][3];
        const int wave = t >> 6, lane = t & 63;
        if (lane == 0) { red[wave][0] = s_all; red[wave][1] = s_r0; red[wave][2] = s_c0; }
        __syncthreads();
        if (t == 0) {
            float a = 0.f, r = 0.f, c = 0.f;
#pragma unroll
            for (int wv = 0; wv < 4; ++wv) { a += red[wv][0]; r += red[wv][1]; c += red[wv][2]; }
            float4 o4; o4.x = a; o4.y = r; o4.z = c; o4.w = x00;
            xs[blk] = o4;
        }
    } else {
        // ---- weight reduce: c = blk - 8192, o = t ----
        const int c = blk - NB * CIN;
        const float* p = w + ((size_t)c * COUT + t) * 9;
        const float w0 = p[0], w1 = p[1], w2 = p[2],
                    w3 = p[3], w4 = p[4], w5 = p[5],
                    w6 = p[6], w7 = p[7], w8 = p[8];
        float4 o4;
        o4.x = w0 + w1 + w2 + w3 + w4 + w5 + w6 + w7 + w8; // Wsum
        o4.y = w0 + w1 + w2;                               // Wr (kh=0)
        o4.z = w0 + w3 + w6;                               // Wc (kw=0)
        o4.w = w0;                                         // W00
        ws4[c * COUT + t] = o4;
    }
}

// ---------------------------------------------------------------------------
// Kernel 2: out[b,o] = 2*( (1/16384)*sum_c(Sx*Wsum - Row0*Wr - Col0*Wc
//                                          + X00*W00) + bias[o] )
// 64 blocks: (b, half-of-o). 1024 threads: thread = (seg 0..7, o-offset 0..127),
// each sums 32 c's; LDS-reduce 8 segments. 1024 waves device-wide.
// ---------------------------------------------------------------------------
__global__ __launch_bounds__(1024) void finalize_kernel(
    const float4* __restrict__ xs, const float4* __restrict__ ws4,
    const float* __restrict__ bias, float* __restrict__ out)
{
    const int b2   = blockIdx.x;
    const int b    = b2 >> 1;
    const int half = b2 & 1;
    const int t    = threadIdx.x;
    const int oo   = t & 127;                 // o-offset within half
    const int seg  = t >> 7;                  // 0..7
    const int o    = half * 128 + oo;

    __shared__ float4 sx[CIN];
    __shared__ float  part[8][128];
    if (t < CIN) sx[t] = xs[b * CIN + t];
    __syncthreads();

    float acc = 0.f;
    const int c0 = seg * 32;
#pragma unroll 8
    for (int i = 0; i < 32; ++i) {
        const int c = c0 + i;
        const float4 s  = sx[c];                          // wave-uniform broadcast
        const float4 wv = ws4[c * COUT + o];              // coalesced float4
        acc += s.x * wv.x - s.y * wv.y - s.z * wv.z + s.w * wv.w;
    }
    part[seg][oo] = acc;
    __syncthreads();
    if (t < 128) {
        float a = 0.f;
#pragma unroll
        for (int sg = 0; sg < 8; ++sg) a += part[sg][t];
        const int oglob = half * 128 + t;
        out[b * COUT + oglob] = MULT * (a * INV_SPATIAL + bias[oglob]);
    }
}

// ---------------------------------------------------------------------------
extern "C" void kernel_launch(void* const* d_in, const int* in_sizes, int n_in,
                              void* d_out, int out_size, void* d_ws, size_t ws_size,
                              hipStream_t stream)
{
    const float* x      = (const float*)d_in[0];   // (32,256,64,64)
    const float* weight = (const float*)d_in[1];   // (256,256,3,3)
    const float* bias   = (const float*)d_in[2];   // (256,)
    float* out = (float*)d_out;                    // (32,256,1,1)

    float4* xs  = (float4*)d_ws;                   // 8192 float4 = 128 KiB
    float4* ws4 = xs + (size_t)NB * CIN;           // 65536 float4 = 1 MiB

    stats_kernel<<<NB * CIN + CIN, 256, 0, stream>>>(x, weight, xs, ws4);
    finalize_kernel<<<NB * 2, 1024, 0, stream>>>(xs, ws4, bias, out);
}